// Round 1
// baseline (29757.767 us; speedup 1.0000x reference)
//
#include <hip/hip_runtime.h>
#include <math.h>

// Problem constants (B, H, V, T from reference)
#define Bb 32
#define Hh 1024
#define Vv 32000
#define Tt 128
#define K2 2048   // 2*H

// ---------------------------------------------------------------------------
// K0: init hidden double-buffer phase 0 and dec_in tokens
// ---------------------------------------------------------------------------
__global__ __launch_bounds__(256) void init_kernel(
    const float* __restrict__ hidden,   // [2][B][H]
    const int* __restrict__ inputs,     // [B]
    float* __restrict__ h0,             // [2][B][H] (phase 0)
    int* __restrict__ dec_in)           // [B]
{
    int i = blockIdx.x * 256 + threadIdx.x;
    if (i < 2 * Bb * Hh) h0[i] = hidden[i];
    if (i < Bb) dec_in[i] = inputs[i];
}

// ---------------------------------------------------------------------------
// K1 (v2): one GRU step, both directions.
// Decomposition transposed vs v1: one THREAD per output element (dir,b,i),
// K-serial per thread with a 2-way K-split across thread halves.
//   grid  = 256 blocks  = 2 dirs x 128 i-blocks (8 i each)
//   block = 512 threads = 2 K-halves x (8 isub x 32 b)
// Weights: streamed from global, each (gate,i) row read by exactly ONE wave
//   -> 50 MB/step total (was 1.6 GB/step with the wave-per-(b,i) layout).
// x/h: staged per K-chunk (KC=256) in LDS, reused by all 8 i's and both
//   K-halves; stride 260 keeps float4 reads at worst 4-way banked.
// No cross-lane butterfly reduce: K-serial accs, one LDS combine of halves.
// ---------------------------------------------------------------------------
#define KC 256

__global__ __launch_bounds__(512) void gru_step_kernel(
    const float* __restrict__ emb,
    const float* __restrict__ wih_f, const float* __restrict__ whh_f,
    const float* __restrict__ bih_f, const float* __restrict__ bhh_f,
    const float* __restrict__ wih_b, const float* __restrict__ whh_b,
    const float* __restrict__ bih_b, const float* __restrict__ bhh_b,
    const float* __restrict__ h_prev,   // [2][B][H]
    float* __restrict__ h_next,         // [2][B][H]
    const int* __restrict__ dec_in)
{
    __shared__ __align__(16) float xs[Bb][260];   // 33280 B
    __shared__ __align__(16) float hs[Bb][260];   // 33280 B
    __shared__ float scr[256][6];                 // 6144 B  (K-half partials)
    __shared__ int   tk[Bb];

    const int tid  = threadIdx.x;
    const int dir  = blockIdx.x >> 7;
    const int i0   = (blockIdx.x & 127) * 8;
    const int kh   = tid >> 8;           // K-half 0/1
    const int t    = tid & 255;
    const int b    = t & 31;
    const int isub = t >> 5;             // 0..7
    const int i    = i0 + isub;

    const float* wih = dir ? wih_b : wih_f;
    const float* whh = dir ? whh_b : whh_f;
    const float* bi  = dir ? bih_b : bih_f;
    const float* bh  = dir ? bhh_b : bhh_f;

    if (tid < Bb) tk[tid] = dec_in[tid];

    // per-thread weight row pointers (2 distinct i's per wave -> 2 txns/load)
    const float* w0 = wih + (size_t)i * Hh;            // i_r
    const float* w1 = wih + (size_t)(Hh + i) * Hh;     // i_z
    const float* w2 = wih + (size_t)(2 * Hh + i) * Hh; // i_n
    const float* v0 = whh + (size_t)i * Hh;            // h_r
    const float* v1 = whh + (size_t)(Hh + i) * Hh;     // h_z
    const float* v2 = whh + (size_t)(2 * Hh + i) * Hh; // h_n
    const float* hrow_base = h_prev + (size_t)dir * Bb * Hh;

    float a0 = 0.f, a1 = 0.f, a2 = 0.f, a3 = 0.f, a4 = 0.f, a5 = 0.f;
    float prev = 0.f;
    const int cprev = i0 >> 8;           // chunk that contains this block's i's

    __syncthreads();                     // tk visible

    for (int c = 0; c < 4; ++c) {
        const int kbase = c * KC;
        if (c) __syncthreads();          // previous chunk fully consumed
        // stage x[32][KC] and h[32][KC]: 4096 float4 slots over 512 threads
        #pragma unroll
        for (int j = 0; j < 4; ++j) {
            const int s  = tid + 512 * j;       // 0..2047
            const int bb = s >> 6;
            const int kf = (s & 63) << 2;
            *(float4*)&xs[bb][kf] =
                *(const float4*)(emb + (size_t)tk[bb] * Hh + kbase + kf);
            *(float4*)&hs[bb][kf] =
                *(const float4*)(hrow_base + (size_t)bb * Hh + kbase + kf);
        }
        __syncthreads();

        if (c == cprev) prev = hs[b][i & (KC - 1)];   // h_prev[dir][b][i]

        const int ko = kbase + kh * 128;  // global k offset of this half
        #pragma unroll 4
        for (int j = 0; j < 32; ++j) {
            const int kl = kh * 128 + 4 * j;          // LDS offset in chunk
            const int kg = ko + 4 * j;                // global k
            const float4 xv = *(const float4*)&xs[b][kl];
            const float4 hv = *(const float4*)&hs[b][kl];
            const float4 p0 = *(const float4*)(w0 + kg);
            const float4 p1 = *(const float4*)(w1 + kg);
            const float4 p2 = *(const float4*)(w2 + kg);
            const float4 q0 = *(const float4*)(v0 + kg);
            const float4 q1 = *(const float4*)(v1 + kg);
            const float4 q2 = *(const float4*)(v2 + kg);
            a0 += xv.x * p0.x + xv.y * p0.y + xv.z * p0.z + xv.w * p0.w;
            a1 += xv.x * p1.x + xv.y * p1.y + xv.z * p1.z + xv.w * p1.w;
            a2 += xv.x * p2.x + xv.y * p2.y + xv.z * p2.z + xv.w * p2.w;
            a3 += hv.x * q0.x + hv.y * q0.y + hv.z * q0.z + hv.w * q0.w;
            a4 += hv.x * q1.x + hv.y * q1.y + hv.z * q1.z + hv.w * q1.w;
            a5 += hv.x * q2.x + hv.y * q2.y + hv.z * q2.z + hv.w * q2.w;
        }
    }

    // combine the two K-halves through LDS, then gates on half 0
    if (kh) {
        scr[t][0] = a0; scr[t][1] = a1; scr[t][2] = a2;
        scr[t][3] = a3; scr[t][4] = a4; scr[t][5] = a5;
    }
    __syncthreads();
    if (!kh) {
        a0 += scr[t][0]; a1 += scr[t][1]; a2 += scr[t][2];
        a3 += scr[t][3]; a4 += scr[t][4]; a5 += scr[t][5];
        const float gr = a0 + a3 + bi[i] + bh[i];
        const float gz = a1 + a4 + bi[Hh + i] + bh[Hh + i];
        const float r  = 1.f / (1.f + expf(-gr));
        const float z  = 1.f / (1.f + expf(-gz));
        const float n  = tanhf(a2 + bi[2 * Hh + i] + r * (a5 + bh[2 * Hh + i]));
        h_next[((size_t)dir * Bb + b) * Hh + i] = (1.f - z) * n + z * prev;
    }
}

// ---------------------------------------------------------------------------
// K2: logits[b][v] = concat(h_f[b],h_b[b]) . w_out[v] + b_out[v]
// written directly into d_out[b][t][v].
// Block: 256 threads = 4 waves; wave kw owns K-quarter. Per-thread tile:
// 4 b's (tb+8i) x 8 v's. h staged in LDS (stride 260 -> conflict-free reads).
// Cross-kw partial sums reduced through LDS at the end.
// ---------------------------------------------------------------------------
#define KT 256
#define HS_STRIDE 260

__global__ __launch_bounds__(256) void logits_kernel(
    const float* __restrict__ h,        // [2][B][H] (current phase)
    const float* __restrict__ w_out,    // [V][2H]
    const float* __restrict__ b_out,    // [V]
    float* __restrict__ out,            // [B][T][V]
    const int t)
{
    __shared__ __align__(16) float hs[Bb * HS_STRIDE];   // 33280 B
    __shared__ __align__(16) float scr[3 * 64 * 32];     // 24576 B

    const int tid = threadIdx.x;
    const int kw  = tid >> 6;            // K quarter 0..3
    const int tb  = tid & 7;             // b group
    const int tv  = (tid >> 3) & 7;      // v group
    const int v0  = blockIdx.x * 64;

    float acc[4][8];
    #pragma unroll
    for (int i = 0; i < 4; ++i)
        #pragma unroll
        for (int j = 0; j < 8; ++j) acc[i][j] = 0.f;

    for (int kt = 0; kt < K2; kt += KT) {
        // stage h[all b][kt..kt+255] into LDS (dir0 rows for kt<H, dir1 after)
        const float* src = h + ((kt >= Hh) ? ((size_t)Bb * Hh + (size_t)(kt - Hh))
                                           : (size_t)kt);
        #pragma unroll
        for (int s = 0; s < 8; ++s) {
            const int f  = tid + 256 * s;      // 0..2047 float4 slots
            const int bb = f >> 6;
            const int kk = (f & 63) << 2;
            *(float4*)(&hs[bb * HS_STRIDE + kk]) =
                *(const float4*)(src + (size_t)bb * Hh + kk);
        }
        __syncthreads();

        const float* wbase = w_out + kt + kw * 64;
        #pragma unroll 2
        for (int kk = 0; kk < 64; kk += 4) {
            const int kl = kw * 64 + kk;
            float4 hv[4];
            #pragma unroll
            for (int i = 0; i < 4; ++i)
                hv[i] = *(const float4*)(&hs[(tb + 8 * i) * HS_STRIDE + kl]);
            #pragma unroll
            for (int j = 0; j < 8; ++j) {
                const float4 w4 =
                    *(const float4*)(wbase + (size_t)(v0 + tv * 8 + j) * K2 + kk);
                #pragma unroll
                for (int i = 0; i < 4; ++i) {
                    acc[i][j] = fmaf(hv[i].x, w4.x, acc[i][j]);
                    acc[i][j] = fmaf(hv[i].y, w4.y, acc[i][j]);
                    acc[i][j] = fmaf(hv[i].z, w4.z, acc[i][j]);
                    acc[i][j] = fmaf(hv[i].w, w4.w, acc[i][j]);
                }
            }
        }
        __syncthreads();
    }

    // reduce partial sums across the 4 K-quarters
    const int l = tid & 63;
    if (kw > 0) {
        float* p = &scr[(size_t)((kw - 1) * 64 + l) * 32];
        #pragma unroll
        for (int i = 0; i < 4; ++i)
            #pragma unroll
            for (int j = 0; j < 8; ++j) p[i * 8 + j] = acc[i][j];
    }
    __syncthreads();
    if (kw == 0) {
        #pragma unroll
        for (int q = 0; q < 3; ++q) {
            const float* p = &scr[(size_t)(q * 64 + l) * 32];
            #pragma unroll
            for (int i = 0; i < 4; ++i)
                #pragma unroll
                for (int j = 0; j < 8; ++j) acc[i][j] += p[i * 8 + j];
        }
        const int v = v0 + tv * 8;
        const float4 bo0 = *(const float4*)(b_out + v);
        const float4 bo1 = *(const float4*)(b_out + v + 4);
        #pragma unroll
        for (int i = 0; i < 4; ++i) {
            const int bb = tb + 8 * i;
            float* o = out + ((size_t)bb * Tt + t) * Vv + v;
            float4 r0 = make_float4(acc[i][0] + bo0.x, acc[i][1] + bo0.y,
                                    acc[i][2] + bo0.z, acc[i][3] + bo0.w);
            float4 r1 = make_float4(acc[i][4] + bo1.x, acc[i][5] + bo1.y,
                                    acc[i][6] + bo1.z, acc[i][7] + bo1.w);
            *(float4*)o = r0;
            *(float4*)(o + 4) = r1;
        }
    }
}

// ---------------------------------------------------------------------------
// K3: per batch row: max+argmax, sumexp, in-place log-softmax, next token.
// One block per b. Argmax tie-break: lowest index (matches jnp.argmax).
// ---------------------------------------------------------------------------
__global__ __launch_bounds__(256) void softmax_kernel(
    float* __restrict__ out,            // [B][T][V]
    int* __restrict__ dec_in,           // [B]
    const int t)
{
    const int b = blockIdx.x;
    float* row = out + ((size_t)b * Tt + t) * Vv;
    const int tid = threadIdx.x;
    const int wave = tid >> 6;

    __shared__ float sm[4];
    __shared__ int   si[4];
    __shared__ float ss[4];
    __shared__ float bc[2];   // [0]=max, [1]=lse
    __shared__ int   bi[1];

    // pass 1: max + argmax (first-index wins)
    float m = -INFINITY;
    int idx = 0x7fffffff;
    for (int v = tid; v < Vv; v += 256) {
        const float xv = row[v];
        if (xv > m) { m = xv; idx = v; }
    }
    #pragma unroll
    for (int off = 32; off > 0; off >>= 1) {
        const float om = __shfl_xor(m, off, 64);
        const int   oi = __shfl_xor(idx, off, 64);
        if (om > m || (om == m && oi < idx)) { m = om; idx = oi; }
    }
    if ((tid & 63) == 0) { sm[wave] = m; si[wave] = idx; }
    __syncthreads();
    if (tid == 0) {
        #pragma unroll
        for (int w = 1; w < 4; ++w)
            if (sm[w] > m || (sm[w] == m && si[w] < idx)) { m = sm[w]; idx = si[w]; }
        bc[0] = m;
        bi[0] = idx;
    }
    __syncthreads();
    m = bc[0];

    // pass 2: sum of exp
    float s = 0.f;
    for (int v = tid; v < Vv; v += 256) s += expf(row[v] - m);
    #pragma unroll
    for (int off = 32; off > 0; off >>= 1) s += __shfl_xor(s, off, 64);
    if ((tid & 63) == 0) ss[wave] = s;
    __syncthreads();
    if (tid == 0) bc[1] = m + logf(ss[0] + ss[1] + ss[2] + ss[3]);
    __syncthreads();
    const float lse = bc[1];

    // pass 3: subtract lse in place
    for (int v = tid; v < Vv; v += 256) row[v] -= lse;

    if (tid == 0) dec_in[b] = bi[0];
}

// ---------------------------------------------------------------------------
extern "C" void kernel_launch(void* const* d_in, const int* in_sizes, int n_in,
                              void* d_out, int out_size, void* d_ws, size_t ws_size,
                              hipStream_t stream) {
    (void)in_sizes; (void)n_in; (void)out_size; (void)ws_size;
    const int*   inputs = (const int*)d_in[0];
    const float* hidden = (const float*)d_in[1];
    const float* emb    = (const float*)d_in[2];
    const float* wih_f  = (const float*)d_in[3];
    const float* whh_f  = (const float*)d_in[4];
    const float* bih_f  = (const float*)d_in[5];
    const float* bhh_f  = (const float*)d_in[6];
    const float* wih_b  = (const float*)d_in[7];
    const float* whh_b  = (const float*)d_in[8];
    const float* bih_b  = (const float*)d_in[9];
    const float* bhh_b  = (const float*)d_in[10];
    const float* w_out  = (const float*)d_in[11];
    const float* b_out  = (const float*)d_in[12];
    float* out = (float*)d_out;

    // workspace layout: 2 phases x [2][B][H] floats, then dec_in ints
    float* hbuf = (float*)d_ws;
    int* dec_in = (int*)((char*)d_ws + (size_t)2 * 2 * Bb * Hh * sizeof(float));
    float* h_ph[2] = { hbuf, hbuf + (size_t)2 * Bb * Hh };

    init_kernel<<<256, 256, 0, stream>>>(hidden, inputs, h_ph[0], dec_in);

    for (int t = 0; t < Tt; ++t) {
        float* hp = h_ph[t & 1];
        float* hn = h_ph[(t + 1) & 1];
        gru_step_kernel<<<256, 512, 0, stream>>>(
            emb, wih_f, whh_f, bih_f, bhh_f,
            wih_b, whh_b, bih_b, bhh_b, hp, hn, dec_in);
        logits_kernel<<<Vv / 64, 256, 0, stream>>>(hn, w_out, b_out, out, t);
        softmax_kernel<<<Bb, 256, 0, stream>>>(out, dec_in, t);
    }
}